// Round 2
// baseline (497.274 us; speedup 1.0000x reference)
//
#include <hip/hip_runtime.h>
#include <hip/hip_cooperative_groups.h>

namespace cg = cooperative_groups;

static constexpr int B_ = 64, PAST = 128, FUTURE = 64, F_ = 51;
static constexpr int N1 = B_ * PAST;    // 8192
static constexpr int N2 = B_ * FUTURE;  // 4096
static constexpr int E1 = N1 * 16;      // 131072
static constexpr int E2 = N2 * 16;      // 65536
static constexpr int MAXDEG = 64;
static constexpr int CSRW = E1 + N1 + E2 + N2;           // 208896
static constexpr int MAXGRID = 1024;                     // 4 blocks/CU * 256 CU

struct GArgs {
    const int *cat1, *cat2, *e1, *e2, *A;
    const float *num1, *num2, *emb0, *emb1, *emb2;
    const float *g1_lin, *g1_asrc, *g1_adst, *g1_b;
    const float *g2_lin, *g2_asrc, *g2_adst, *g2_b, *W;
    int *count1, *slot1, *count2, *slot2, *maskT;
    float *h1, *asrc1, *adst1, *y1, *P2, *h2b, *P1T, *n1w, *h2g, *out;
};

// node feature t of _pre(): [emb0[c0] (16) | emb1[c1] (8) | emb2[c2] (24) | num (3)]
__device__ __forceinline__
float node_feat(const int* cat, const float* num, const float* e0, const float* e1,
                const float* e2, int n, int t) {
    if (t < 16) return e0[cat[n * 3 + 0] * 16 + t];
    if (t < 24) return e1[cat[n * 3 + 1] * 8 + (t - 16)];
    if (t < 48) return e2[cat[n * 3 + 2] * 24 + (t - 24)];
    return num[n * 3 + (t - 48)];
}

// Phase 1: CSR build (counts pre-zeroed by memset) + transposed mask + node prep.
// All loops grid-stride; __syncthreads use is block-uniform.
__device__ void phase_prep(const GArgs& a, float* S) {
    const int t = threadIdx.x, blk = blockIdx.x;
    const int nthread = gridDim.x * 256;
    for (int i = blk * 256 + t; i < CSRW + FUTURE * PAST; i += nthread) {
        if (i < E1) {
            int src = a.e1[i], dst = a.e1[E1 + i];
            int pos = atomicAdd(&a.count1[dst], 1);
            if (pos < MAXDEG) a.slot1[dst * MAXDEG + pos] = src;
        } else if (i < E1 + N1) {
            int n = i - E1;
            int pos = atomicAdd(&a.count1[n], 1);
            if (pos < MAXDEG) a.slot1[n * MAXDEG + pos] = n;
        } else if (i < E1 + N1 + E2) {
            int k = i - E1 - N1;
            int src = a.e2[k], dst = a.e2[E2 + k];
            int pos = atomicAdd(&a.count2[dst], 1);
            if (pos < MAXDEG) a.slot2[dst * MAXDEG + pos] = src;
        } else if (i < CSRW) {
            int n = i - E1 - N1 - E2;
            int pos = atomicAdd(&a.count2[n], 1);
            if (pos < MAXDEG) a.slot2[n * MAXDEG + pos] = n;
        } else {
            int k = i - CSRW;                     // k = f*128 + p
            int f = k >> 7, pp = k & 127;
            a.maskT[k] = a.A[pp * 192 + PAST + f];
        }
    }
    float* xrow = S;
    float* redS = S + 64;
    float* redD = S + 264;
    for (int vb = blk; vb < N1 + N2; vb += gridDim.x) {   // block-uniform vb
        __syncthreads();                                  // xrow/red reuse guard
        if (vb < N1) {                                    // past node
            int n = vb;
            if (t < F_) {
                float xv = node_feat(a.cat1, a.num1, a.emb0, a.emb1, a.emb2, n, t);
                xrow[t] = xv;
                if (t == 50) a.y1[n] = xv;                // y_past = x[:, 50]
            }
            __syncthreads();
            if (t < 200) {
                float acc = 0.f;
                for (int j = 0; j < F_; ++j) acc += xrow[j] * a.g1_lin[j * 200 + t];
                a.h1[n * 200 + t] = acc;
                redS[t] = acc * a.g1_asrc[t];             // flat t == h*50+c
                redD[t] = acc * a.g1_adst[t];
            }
            __syncthreads();
            if (t < 4) {
                float s = 0.f;
                for (int c = 0; c < 50; ++c) s += redS[t * 50 + c];
                a.asrc1[n * 4 + t] = s;
            } else if (t < 8) {
                int h = t - 4;
                float s = 0.f;
                for (int c = 0; c < 50; ++c) s += redD[h * 50 + c];
                a.adst1[n * 4 + h] = s;
            }
        } else {                                          // future node
            int n = vb - N1;
            if (t < F_) {
                float xv = node_feat(a.cat2, a.num2, a.emb0, a.emb1, a.emb2, n, t);
                xrow[t] = xv;
            }
            __syncthreads();
            if (t < 64) {                                 // P2 = x2[:, :50] @ W
                float acc = 0.f;
                for (int j = 0; j < 50; ++j) acc += xrow[j] * a.W[j * 64 + t];
                a.P2[n * 64 + t] = acc;
            } else if (t < 68) {                          // attn-independent h2 part
                int h = t - 64;
                float acc = 0.f;
                for (int j = 0; j < 50; ++j) acc += xrow[j] * a.g2_lin[j * 4 + h];
                a.h2b[n * 4 + h] = acc;
            }
        }
    }
}

// Phase 2: GAT1 aggregation, one wave per dst node; fused x1 -> P projection.
// Wave-private LDS slices; DS ops are in-order per wave -> no block barrier.
__device__ void phase_gat1(const GArgs& a, float* S) {
    const int t = threadIdx.x, lane = t & 63, wv = t >> 6;
    int*    Ssrc = (int*)S + wv * 64;                 // S[0..255]
    float4* Sw   = (float4*)(S + 256) + wv * 64;      // S[256..1279]
    float*  Sx   = S + 1280 + wv * 64;                // S[1280..1535]
    const int wstride = gridDim.x * 4;
    for (int n = blockIdx.x * 4 + wv; n < N1; n += wstride) {
        int deg = min(a.count1[n], MAXDEG);
        int my_src = (lane < deg) ? a.slot1[n * MAXDEG + lane] : 0;
        float ad0 = a.adst1[n * 4 + 0], ad1 = a.adst1[n * 4 + 1];
        float ad2 = a.adst1[n * 4 + 2], ad3 = a.adst1[n * 4 + 3];
        float ex0 = 0.f, ex1 = 0.f, ex2 = 0.f, ex3 = 0.f;
        if (lane < deg) {
            float e0 = a.asrc1[my_src * 4 + 0] + ad0;
            float e1 = a.asrc1[my_src * 4 + 1] + ad1;
            float e2 = a.asrc1[my_src * 4 + 2] + ad2;
            float e3 = a.asrc1[my_src * 4 + 3] + ad3;
            e0 = e0 >= 0.f ? e0 : 0.2f * e0;  ex0 = __expf(e0);
            e1 = e1 >= 0.f ? e1 : 0.2f * e1;  ex1 = __expf(e1);
            e2 = e2 >= 0.f ? e2 : 0.2f * e2;  ex2 = __expf(e2);
            e3 = e3 >= 0.f ? e3 : 0.2f * e3;  ex3 = __expf(e3);
        }
        float s0 = ex0, s1 = ex1, s2 = ex2, s3 = ex3;
        #pragma unroll
        for (int m = 32; m >= 1; m >>= 1) {
            s0 += __shfl_xor(s0, m);
            s1 += __shfl_xor(s1, m);
            s2 += __shfl_xor(s2, m);
            s3 += __shfl_xor(s3, m);
        }
        Ssrc[lane] = my_src;
        Sw[lane] = make_float4(ex0 / (s0 + 1e-16f), ex1 / (s1 + 1e-16f),
                               ex2 / (s2 + 1e-16f), ex3 / (s3 + 1e-16f));
        float acc0 = 0.f, acc1 = 0.f, acc2 = 0.f, acc3 = 0.f;
        for (int i = 0; i < deg; ++i) {
            int srci = Ssrc[i];
            float4 w = Sw[i];                         // broadcast, conflict-free
            if (lane < 50) {
                const float* hr = &a.h1[srci * 200];
                acc0 += w.x * hr[lane];
                acc1 += w.y * hr[50 + lane];
                acc2 += w.z * hr[100 + lane];
                acc3 += w.w * hr[150 + lane];
            }
        }
        if (lane < 50)
            Sx[lane] = 0.25f * (acc0 + acc1 + acc2 + acc3) + a.g1_b[lane];
        float av = 0.f;
        for (int j = 0; j < 50; ++j) av += Sx[j] * a.W[j * 64 + lane];
        int b = n >> 7, p = n & 127;
        a.P1T[b * 8192 + lane * 128 + p] = av;        // transposed store [b][k][p]
        float sq = av * av;                           // ||P1 row||^2
        #pragma unroll
        for (int m = 32; m >= 1; m >>= 1) sq += __shfl_xor(sq, m);
        if (lane == 0) a.n1w[n] = sq;
    }
}

// Phase 3: attention + tmp + h2 finalize. One f per wave; norm expansion
// alpha_p = 2*dot(P1_p,P2_f) - ||P1_p||^2 (||P2_f||^2 constant per row, dropped).
__device__ void phase_attn(const GArgs& a, float* S) {
    float* P1s = S;                                   // [k][p] linear, 8192
    float* ys  = S + 8192;
    float* n1s = S + 8320;
    const int t = threadIdx.x, lane = t & 63, wv = t >> 6;
    for (int task = blockIdx.x; task < B_ * 16; task += gridDim.x) {
        __syncthreads();                              // LDS reuse guard
        int b = task >> 4, fg = task & 15;
        const float4* src4 = (const float4*)(a.P1T + b * 8192);
        float4* dst4 = (float4*)P1s;
        #pragma unroll
        for (int i = 0; i < 8; ++i) dst4[t + i * 256] = src4[t + i * 256];
        if (t < 128) {
            ys[t]  = a.y1[b * 128 + t];
            n1s[t] = a.n1w[b * 128 + t];
        }
        __syncthreads();
        int f = (fg << 2) + wv;
        int q = b * 64 + f;
        float p2k = a.P2[q * 64 + lane];              // lane holds k-th component
        float dota = 0.f, dotb = 0.f;
        const float2* P12 = (const float2*)P1s;       // (k, p=2*lane[+1])
        #pragma unroll
        for (int k = 0; k < 64; ++k) {
            float bk = __shfl(p2k, k);
            float2 v = P12[k * 64 + lane];
            dota += v.x * bk;
            dotb += v.y * bk;
        }
        int2  mm = ((const int2*)a.maskT)[f * 64 + lane];
        float2 nv = ((const float2*)n1s)[lane];
        float sva = mm.x ? (2.f * dota - nv.x) : -1e30f;
        float svb = mm.y ? (2.f * dotb - nv.y) : -1e30f;
        float mx = fmaxf(sva, svb);
        #pragma unroll
        for (int m = 32; m >= 1; m >>= 1) mx = fmaxf(mx, __shfl_xor(mx, m));
        float wa = mm.x ? __expf(sva - mx) : 0.f;
        float wb = mm.y ? __expf(svb - mx) : 0.f;
        float2 yv = ((const float2*)ys)[lane];
        float sw = wa + wb;
        float sy = wa * yv.x + wb * yv.y;
        #pragma unroll
        for (int m = 32; m >= 1; m >>= 1) {
            sw += __shfl_xor(sw, m);
            sy += __shfl_xor(sy, m);
        }
        float tsh = sy / sw;
        if (lane < 4)                                 // h2 = h2base + tmp*g2_lin[50]
            a.h2g[q * 4 + lane] = a.h2b[q * 4 + lane] + tsh * a.g2_lin[200 + lane];
    }
}

// Phase 4: GAT2 aggregation (out_ch=1): one wave per dst node. No LDS.
__device__ void phase_gat2(const GArgs& a) {
    const int t = threadIdx.x, lane = t & 63, wv = t >> 6;
    for (int n = blockIdx.x * 4 + wv; n < N2; n += gridDim.x * 4) {
        int deg = min(a.count2[n], MAXDEG);
        int my_src = (lane < deg) ? a.slot2[n * MAXDEG + lane] : 0;
        float ex[4], nm[4], adterm[4], as[4];
        #pragma unroll
        for (int h = 0; h < 4; ++h) {
            as[h] = a.g2_asrc[h];
            adterm[h] = a.h2g[n * 4 + h] * a.g2_adst[h];
            ex[h] = 0.f; nm[h] = 0.f;
        }
        if (lane < deg) {
            #pragma unroll
            for (int h = 0; h < 4; ++h) {
                float hs = a.h2g[my_src * 4 + h];
                float e = hs * as[h] + adterm[h];
                e = e >= 0.f ? e : 0.2f * e;
                float xv = __expf(e);
                ex[h] = xv;
                nm[h] = xv * hs;
            }
        }
        #pragma unroll
        for (int m = 32; m >= 1; m >>= 1) {
            #pragma unroll
            for (int h = 0; h < 4; ++h) {
                ex[h] += __shfl_xor(ex[h], m);
                nm[h] += __shfl_xor(nm[h], m);
            }
        }
        if (lane == 0) {
            float o = 0.f;
            #pragma unroll
            for (int h = 0; h < 4; ++h) o += nm[h] / (ex[h] + 1e-16f);
            a.out[n] = 0.25f * o + a.g2_b[0];
        }
    }
}

// Single cooperative kernel: {CSR+prep} -> {GAT1} -> {attn} -> {GAT2}.
__global__ __launch_bounds__(256, 4) void k_mega(GArgs a) {
    cg::grid_group grid = cg::this_grid();
    __shared__ __align__(16) float S[8448];           // 33792 B -> 4 blocks/CU
    phase_prep(a, S);
    grid.sync();
    phase_gat1(a, S);
    grid.sync();
    phase_attn(a, S);
    grid.sync();
    phase_gat2(a);
}

// Non-cooperative fallback wrappers (same phases, grid-stride -> any grid works).
__global__ __launch_bounds__(256, 4) void k_p1(GArgs a) {
    __shared__ __align__(16) float S[8448];
    phase_prep(a, S);
}
__global__ __launch_bounds__(256, 4) void k_p2(GArgs a) {
    __shared__ __align__(16) float S[8448];
    phase_gat1(a, S);
}
__global__ __launch_bounds__(256, 4) void k_p3(GArgs a) {
    __shared__ __align__(16) float S[8448];
    phase_attn(a, S);
}
__global__ __launch_bounds__(256, 4) void k_p4(GArgs a) {
    phase_gat2(a);
}

extern "C" void kernel_launch(void* const* d_in, const int* in_sizes, int n_in,
                              void* d_out, int out_size, void* d_ws, size_t ws_size,
                              hipStream_t stream) {
    GArgs a;
    a.cat1    = (const int*)  d_in[0];
    a.num1    = (const float*)d_in[1];
    a.cat2    = (const int*)  d_in[2];
    a.num2    = (const float*)d_in[3];
    a.e1      = (const int*)  d_in[4];
    a.e2      = (const int*)  d_in[5];
    a.A       = (const int*)  d_in[6];
    a.emb0    = (const float*)d_in[7];
    a.emb1    = (const float*)d_in[8];
    a.emb2    = (const float*)d_in[9];
    a.g1_lin  = (const float*)d_in[10];
    a.g1_asrc = (const float*)d_in[11];
    a.g1_adst = (const float*)d_in[12];
    a.g1_b    = (const float*)d_in[13];
    a.g2_lin  = (const float*)d_in[14];
    a.g2_asrc = (const float*)d_in[15];
    a.g2_adst = (const float*)d_in[16];
    a.g2_b    = (const float*)d_in[17];
    a.W       = (const float*)d_in[18];

    // workspace layout (fp32/int32 elements)
    a.count1 = (int*)d_ws;                            // N1 (count1+count2 contiguous)
    a.count2 = a.count1 + N1;                         // N2
    a.slot1  = a.count2 + N2;                         // N1*64
    a.slot2  = a.slot1 + N1 * MAXDEG;                 // N2*64
    a.maskT  = a.slot2 + N2 * MAXDEG;                 // 64*128 (8B-aligned)
    a.h1     = (float*)(a.maskT + FUTURE * PAST);     // N1*200
    a.asrc1  = a.h1 + N1 * 200;                       // N1*4
    a.adst1  = a.asrc1 + N1 * 4;                      // N1*4
    a.y1     = a.adst1 + N1 * 4;                      // N1
    a.P1T    = a.y1 + N1;                             // N1*64 [b][k][p] (16B-aligned)
    a.P2     = a.P1T + N1 * 64;                       // N2*64
    a.h2b    = a.P2 + N2 * 64;                        // N2*4
    a.h2g    = a.h2b + N2 * 4;                        // N2*4
    a.n1w    = a.h2g + N2 * 4;                        // N1
    a.out    = (float*)d_out;

    static int grid_blocks = 0;
    if (grid_blocks == 0) {                           // host-only queries: capture-safe
        int per_cu = 0;
        if (hipOccupancyMaxActiveBlocksPerMultiprocessor(&per_cu, k_mega, 256, 0)
                != hipSuccess || per_cu < 1)
            per_cu = 4;
        int dev = 0, ncu = 0;
        hipGetDevice(&dev);
        if (hipDeviceGetAttribute(&ncu, hipDeviceAttributeMultiprocessorCount, dev)
                != hipSuccess || ncu < 1)
            ncu = 256;
        long g = (long)per_cu * (long)ncu;
        grid_blocks = (int)(g > MAXGRID ? MAXGRID : g);
    }

    hipMemsetAsync(a.count1, 0, (N1 + N2) * sizeof(int), stream);
    void* kargs[] = { (void*)&a };
    hipError_t err = hipLaunchCooperativeKernel(k_mega, dim3(grid_blocks), dim3(256),
                                                kargs, 0, stream);
    if (err != hipSuccess) {                          // fallback: 4 regular launches
        k_p1<<<MAXGRID, 256, 0, stream>>>(a);
        k_p2<<<MAXGRID, 256, 0, stream>>>(a);
        k_p3<<<MAXGRID, 256, 0, stream>>>(a);
        k_p4<<<MAXGRID, 256, 0, stream>>>(a);
    }
}

// Round 3
// 156.399 us; speedup vs baseline: 3.1795x; 3.1795x over previous
//
#include <hip/hip_runtime.h>

static constexpr int B_ = 64, PAST = 128, FUTURE = 64, F_ = 51;
static constexpr int N1 = B_ * PAST;    // 8192
static constexpr int N2 = B_ * FUTURE;  // 4096
static constexpr int E1 = N1 * 16;      // 131072
static constexpr int E2 = N2 * 16;      // 65536
static constexpr int MAXDEG = 64;
static constexpr int CSR_TOT = E1 + N1 + E2 + N2 + FUTURE * PAST;  // 217088
static constexpr int NB_CSR = CSR_TOT / 256;                       // 848
static constexpr int NPB = 16;                                     // nodes per block
static constexpr int NBP = N1 / NPB;                               // 512 past blocks
static constexpr int NBF = N2 / NPB;                               // 256 future blocks

// node feature t of _pre(): [emb0[c0] (16) | emb1[c1] (8) | emb2[c2] (24) | num (3)]
__device__ __forceinline__
float node_feat(const int* cat, const float* num, const float* e0, const float* e1,
                const float* e2, int n, int t) {
    if (t < 16) return e0[cat[n * 3 + 0] * 16 + t];
    if (t < 24) return e1[cat[n * 3 + 1] * 8 + (t - 16)];
    if (t < 48) return e2[cat[n * 3 + 2] * 24 + (t - 24)];
    return num[n * 3 + (t - 48)];
}

// K1 (fused): blocks [0,NB_CSR): CSR build (counts pre-zeroed by memset) + maskT.
// Blocks [NB_CSR, +NBP): 16 past nodes each -> h1, asrc1, adst1, y1 (register-
// blocked: g1_lin column read once, used for 16 nodes). Blocks [.., +NBF): 16
// future nodes each -> P2 = x2@W, h2b = x2[:,:50]@g2_lin.
__global__ __launch_bounds__(256) void k_prep(
        const int* __restrict__ cat1, const float* __restrict__ num1,
        const int* __restrict__ cat2, const float* __restrict__ num2,
        const float* __restrict__ emb0, const float* __restrict__ emb1,
        const float* __restrict__ emb2,
        const float* __restrict__ g1_lin, const float* __restrict__ g1_asrc,
        const float* __restrict__ g1_adst, const float* __restrict__ W,
        const float* __restrict__ g2_lin,
        const int* __restrict__ e1, const int* __restrict__ e2,
        const int* __restrict__ A,
        float* __restrict__ h1, float* __restrict__ asrc1, float* __restrict__ adst1,
        float* __restrict__ y1, float* __restrict__ P2, float* __restrict__ h2b,
        int* __restrict__ count1, int* __restrict__ slot1,
        int* __restrict__ count2, int* __restrict__ slot2, int* __restrict__ maskT) {
    int blk = blockIdx.x, t = threadIdx.x;
    if (blk < NB_CSR) {                           // CSR part (independent of prep)
        int i = blk * 256 + t;
        if (i < E1) {
            int src = e1[i], dst = e1[E1 + i];
            int pos = atomicAdd(&count1[dst], 1);
            if (pos < MAXDEG) slot1[dst * MAXDEG + pos] = src;
        } else if (i < E1 + N1) {
            int n = i - E1;
            int pos = atomicAdd(&count1[n], 1);
            if (pos < MAXDEG) slot1[n * MAXDEG + pos] = n;
        } else if (i < E1 + N1 + E2) {
            int k = i - E1 - N1;
            int src = e2[k], dst = e2[E2 + k];
            int pos = atomicAdd(&count2[dst], 1);
            if (pos < MAXDEG) slot2[dst * MAXDEG + pos] = src;
        } else if (i < E1 + N1 + E2 + N2) {
            int n = i - E1 - N1 - E2;
            int pos = atomicAdd(&count2[n], 1);
            if (pos < MAXDEG) slot2[n * MAXDEG + pos] = n;
        } else if (i < CSR_TOT) {
            int k = i - (E1 + N1 + E2 + N2);      // k = f*128 + p
            int f = k >> 7, pp = k & 127;
            maskT[k] = A[pp * 192 + PAST + f];
        }
        return;
    }
    __shared__ __align__(16) float xr[NPB][64];   // [nn][j], j<51 valid, rest 0
    __shared__ float SredS[NPB][200];
    __shared__ float SredD[NPB][200];
    bool past = (blk < NB_CSR + NBP);
    int n0 = past ? (blk - NB_CSR) * NPB : (blk - NB_CSR - NBP) * NPB;
    // stage 16 x-rows (zero-padded to 64 cols so float4 reads never see garbage)
    #pragma unroll
    for (int r = 0; r < 4; ++r) {
        int i = t + r * 256, nn = i >> 6, tt = i & 63;
        float xv = 0.f;
        if (tt < F_) {
            xv = past ? node_feat(cat1, num1, emb0, emb1, emb2, n0 + nn, tt)
                      : node_feat(cat2, num2, emb0, emb1, emb2, n0 + nn, tt);
            if (past && tt == 50) y1[n0 + nn] = xv;   // y_past = x[:, 50]
        }
        xr[nn][tt] = xv;
    }
    __syncthreads();
    const float4* xr4 = (const float4*)&xr[0][0];     // [nn*16 + j4]
    if (past) {
        if (t < 200) {
            float acc[NPB];
            #pragma unroll
            for (int nn = 0; nn < NPB; ++nn) acc[nn] = 0.f;
            #pragma unroll
            for (int j4 = 0; j4 < 13; ++j4) {         // j = 4*j4 + {0,1,2,3}
                int j = j4 * 4;
                float g0 = g1_lin[(j + 0) * 200 + t];
                float g1 = g1_lin[(j + 1) * 200 + t];
                float g2 = g1_lin[(j + 2) * 200 + t];
                float g3 = (j + 3 < F_) ? g1_lin[(j + 3) * 200 + t] : 0.f;
                #pragma unroll
                for (int nn = 0; nn < NPB; ++nn) {
                    float4 xv = xr4[nn * 16 + j4];    // broadcast LDS read
                    acc[nn] = fmaf(xv.x, g0, acc[nn]);
                    acc[nn] = fmaf(xv.y, g1, acc[nn]);
                    acc[nn] = fmaf(xv.z, g2, acc[nn]);
                    acc[nn] = fmaf(xv.w, g3, acc[nn]);
                }
            }
            float as_ = g1_asrc[t], ad_ = g1_adst[t]; // flat t == h*50+c
            #pragma unroll
            for (int nn = 0; nn < NPB; ++nn) {
                h1[(n0 + nn) * 200 + t] = acc[nn];
                SredS[nn][t] = acc[nn] * as_;
                SredD[nn][t] = acc[nn] * ad_;
            }
        }
        __syncthreads();
        if (t < 128) {                                // (nn, h, S/D) per thread
            int nn = t >> 3, h = (t >> 1) & 3;
            const float* row = (t & 1) ? &SredD[nn][h * 50] : &SredS[nn][h * 50];
            float s = 0.f;
            for (int c = 0; c < 50; ++c) s += row[c];
            float* dstp = (t & 1) ? adst1 : asrc1;
            dstp[(n0 + nn) * 4 + h] = s;
        }
    } else {
        if (t < 64) {                                 // P2 = x2[:, :50] @ W
            float acc[NPB];
            #pragma unroll
            for (int nn = 0; nn < NPB; ++nn) acc[nn] = 0.f;
            #pragma unroll
            for (int j4 = 0; j4 < 13; ++j4) {
                int j = j4 * 4;
                float g0 = (j + 0 < 50) ? W[(j + 0) * 64 + t] : 0.f;
                float g1 = (j + 1 < 50) ? W[(j + 1) * 64 + t] : 0.f;
                float g2 = (j + 2 < 50) ? W[(j + 2) * 64 + t] : 0.f;
                float g3 = (j + 3 < 50) ? W[(j + 3) * 64 + t] : 0.f;
                #pragma unroll
                for (int nn = 0; nn < NPB; ++nn) {
                    float4 xv = xr4[nn * 16 + j4];
                    acc[nn] = fmaf(xv.x, g0, acc[nn]);
                    acc[nn] = fmaf(xv.y, g1, acc[nn]);
                    acc[nn] = fmaf(xv.z, g2, acc[nn]);
                    acc[nn] = fmaf(xv.w, g3, acc[nn]);
                }
            }
            #pragma unroll
            for (int nn = 0; nn < NPB; ++nn) P2[(n0 + nn) * 64 + t] = acc[nn];
        } else if (t < 128) {                         // h2b: one (node, head) each
            int nn = (t - 64) >> 2, h = (t - 64) & 3;
            float acc = 0.f;
            for (int j = 0; j < 50; ++j) acc += xr[nn][j] * g2_lin[j * 4 + h];
            h2b[(n0 + nn) * 4 + h] = acc;
        }
    }
}

// K2: GAT1 aggregation, one wave per dst node; fused x1 -> P projection.
// Writes P transposed per graph: P1T[b][k][p] and row norm n1w.
__global__ __launch_bounds__(256) void k_gat1(
        const int* __restrict__ count1, const int* __restrict__ slot1,
        const float* __restrict__ h1, const float* __restrict__ asrc1,
        const float* __restrict__ adst1, const float* __restrict__ g1_b,
        const float* __restrict__ W, float* __restrict__ P1T,
        float* __restrict__ n1w) {
    __shared__ int    Ssrc[4][64];
    __shared__ float4 Sw[4][64];
    __shared__ float  Sx[4][64];
    int t = threadIdx.x, lane = t & 63, wv = t >> 6;
    int n = (blockIdx.x * 256 + t) >> 6;          // one node per wave (grid exact)
    int deg = min(count1[n], MAXDEG);
    int my_src = (lane < deg) ? slot1[n * MAXDEG + lane] : 0;
    float ad0 = adst1[n * 4 + 0], ad1 = adst1[n * 4 + 1];
    float ad2 = adst1[n * 4 + 2], ad3 = adst1[n * 4 + 3];
    float ex0 = 0.f, ex1 = 0.f, ex2 = 0.f, ex3 = 0.f;
    if (lane < deg) {
        float e0 = asrc1[my_src * 4 + 0] + ad0;
        float e1 = asrc1[my_src * 4 + 1] + ad1;
        float e2 = asrc1[my_src * 4 + 2] + ad2;
        float e3 = asrc1[my_src * 4 + 3] + ad3;
        e0 = e0 >= 0.f ? e0 : 0.2f * e0;  ex0 = __expf(e0);
        e1 = e1 >= 0.f ? e1 : 0.2f * e1;  ex1 = __expf(e1);
        e2 = e2 >= 0.f ? e2 : 0.2f * e2;  ex2 = __expf(e2);
        e3 = e3 >= 0.f ? e3 : 0.2f * e3;  ex3 = __expf(e3);
    }
    float s0 = ex0, s1 = ex1, s2 = ex2, s3 = ex3;
    #pragma unroll
    for (int m = 32; m >= 1; m >>= 1) {
        s0 += __shfl_xor(s0, m);
        s1 += __shfl_xor(s1, m);
        s2 += __shfl_xor(s2, m);
        s3 += __shfl_xor(s3, m);
    }
    Ssrc[wv][lane] = my_src;
    Sw[wv][lane] = make_float4(ex0 / (s0 + 1e-16f), ex1 / (s1 + 1e-16f),
                               ex2 / (s2 + 1e-16f), ex3 / (s3 + 1e-16f));
    __syncthreads();
    float acc0 = 0.f, acc1 = 0.f, acc2 = 0.f, acc3 = 0.f;
    for (int i = 0; i < deg; ++i) {
        int srci = Ssrc[wv][i];
        float4 w = Sw[wv][i];                     // broadcast, conflict-free
        if (lane < 50) {
            const float* hr = &h1[srci * 200];
            acc0 += w.x * hr[lane];
            acc1 += w.y * hr[50 + lane];
            acc2 += w.z * hr[100 + lane];
            acc3 += w.w * hr[150 + lane];
        }
    }
    if (lane < 50)
        Sx[wv][lane] = 0.25f * (acc0 + acc1 + acc2 + acc3) + g1_b[lane];
    __syncthreads();
    float a = 0.f;
    for (int j = 0; j < 50; ++j) a += Sx[wv][j] * W[j * 64 + lane];
    int b = n >> 7, p = n & 127;
    P1T[b * 8192 + lane * 128 + p] = a;           // transposed store [b][k][p]
    float sq = a * a;                             // ||P1 row||^2 via wave reduce
    #pragma unroll
    for (int m = 32; m >= 1; m >>= 1) sq += __shfl_xor(sq, m);
    if (lane == 0) n1w[n] = sq;
}

// K3: attention + tmp + h2 finalize. One f per wave; norm expansion:
// alpha_p = 2*dot(P1_p,P2_f) - ||P1_p||^2 (||P2_f||^2 constant per row, dropped).
__global__ __launch_bounds__(256) void k_attn(
        const float* __restrict__ P1T, const float* __restrict__ P2,
        const int* __restrict__ maskT, const float* __restrict__ y1,
        const float* __restrict__ n1w, const float* __restrict__ h2b,
        const float* __restrict__ g2_lin, float* __restrict__ h2g) {
    __shared__ __align__(16) float P1s[8192];     // [k][p] linear
    __shared__ __align__(16) float ys[128];
    __shared__ __align__(16) float n1s[128];
    int b = blockIdx.x >> 4, fg = blockIdx.x & 15;
    int t = threadIdx.x, lane = t & 63, wv = t >> 6;
    const float4* src4 = (const float4*)(P1T + b * 8192);
    float4* dst4 = (float4*)P1s;
    #pragma unroll
    for (int i = 0; i < 8; ++i) dst4[t + i * 256] = src4[t + i * 256];
    if (t < 128) {
        ys[t]  = y1[b * 128 + t];
        n1s[t] = n1w[b * 128 + t];
    }
    __syncthreads();
    int f = (fg << 2) + wv;
    int q = b * 64 + f;
    float p2k = P2[q * 64 + lane];                // lane holds k-th component
    float dota = 0.f, dotb = 0.f;
    const float2* P12 = (const float2*)P1s;       // element (k, p=2*lane[+1])
    #pragma unroll
    for (int k = 0; k < 64; ++k) {
        float bk = __shfl(p2k, k);
        float2 v = P12[k * 64 + lane];
        dota += v.x * bk;
        dotb += v.y * bk;
    }
    int2  mm  = ((const int2*)maskT)[f * 64 + lane];
    float2 nv = ((const float2*)n1s)[lane];
    float va = mm.x ? (2.f * dota - nv.x) : -1e30f;
    float vb = mm.y ? (2.f * dotb - nv.y) : -1e30f;
    float mx = fmaxf(va, vb);
    #pragma unroll
    for (int m = 32; m >= 1; m >>= 1) mx = fmaxf(mx, __shfl_xor(mx, m));
    float wa = mm.x ? __expf(va - mx) : 0.f;
    float wb = mm.y ? __expf(vb - mx) : 0.f;
    float2 yv = ((const float2*)ys)[lane];
    float sw = wa + wb;
    float sy = wa * yv.x + wb * yv.y;
    #pragma unroll
    for (int m = 32; m >= 1; m >>= 1) {
        sw += __shfl_xor(sw, m);
        sy += __shfl_xor(sy, m);
    }
    float tsh = sy / sw;
    if (lane < 4)                                 // h2 = h2base + tmp * g2_lin[50]
        h2g[q * 4 + lane] = h2b[q * 4 + lane] + tsh * g2_lin[50 * 4 + lane];
}

// K4: GAT2 aggregation (out_ch=1): one wave per dst node.
__global__ __launch_bounds__(256) void k_gat2(
        const int* __restrict__ count2, const int* __restrict__ slot2,
        const float* __restrict__ h2g, const float* __restrict__ g2_asrc,
        const float* __restrict__ g2_adst, const float* __restrict__ g2_b,
        float* __restrict__ out) {
    int wave = (blockIdx.x * blockDim.x + threadIdx.x) >> 6;
    int lane = threadIdx.x & 63;
    if (wave >= N2) return;
    int n = wave;
    int deg = min(count2[n], MAXDEG);
    int my_src = (lane < deg) ? slot2[n * MAXDEG + lane] : 0;
    float ex[4], nm[4], adterm[4], as[4];
    #pragma unroll
    for (int h = 0; h < 4; ++h) {
        as[h] = g2_asrc[h];
        adterm[h] = h2g[n * 4 + h] * g2_adst[h];
        ex[h] = 0.f; nm[h] = 0.f;
    }
    if (lane < deg) {
        #pragma unroll
        for (int h = 0; h < 4; ++h) {
            float hs = h2g[my_src * 4 + h];
            float e = hs * as[h] + adterm[h];
            e = e >= 0.f ? e : 0.2f * e;
            float xv = __expf(e);
            ex[h] = xv;
            nm[h] = xv * hs;
        }
    }
    #pragma unroll
    for (int m = 32; m >= 1; m >>= 1) {
        #pragma unroll
        for (int h = 0; h < 4; ++h) {
            ex[h] += __shfl_xor(ex[h], m);
            nm[h] += __shfl_xor(nm[h], m);
        }
    }
    if (lane == 0) {
        float o = 0.f;
        #pragma unroll
        for (int h = 0; h < 4; ++h) o += nm[h] / (ex[h] + 1e-16f);
        out[n] = 0.25f * o + g2_b[0];
    }
}

extern "C" void kernel_launch(void* const* d_in, const int* in_sizes, int n_in,
                              void* d_out, int out_size, void* d_ws, size_t ws_size,
                              hipStream_t stream) {
    const int*   cat1    = (const int*)  d_in[0];
    const float* num1    = (const float*)d_in[1];
    const int*   cat2    = (const int*)  d_in[2];
    const float* num2    = (const float*)d_in[3];
    const int*   e1      = (const int*)  d_in[4];
    const int*   e2      = (const int*)  d_in[5];
    const int*   A       = (const int*)  d_in[6];
    const float* emb0    = (const float*)d_in[7];
    const float* emb1    = (const float*)d_in[8];
    const float* emb2    = (const float*)d_in[9];
    const float* g1_lin  = (const float*)d_in[10];
    const float* g1_asrc = (const float*)d_in[11];
    const float* g1_adst = (const float*)d_in[12];
    const float* g1_b    = (const float*)d_in[13];
    const float* g2_lin  = (const float*)d_in[14];
    const float* g2_asrc = (const float*)d_in[15];
    const float* g2_adst = (const float*)d_in[16];
    const float* g2_b    = (const float*)d_in[17];
    const float* W       = (const float*)d_in[18];
    float* out = (float*)d_out;

    // workspace layout (fp32/int32 elements)
    int*   count1 = (int*)d_ws;                   // N1  (count1+count2 contiguous!)
    int*   count2 = count1 + N1;                  // N2
    int*   slot1  = count2 + N2;                  // N1*64
    int*   slot2  = slot1 + N1 * MAXDEG;          // N2*64
    int*   maskT  = slot2 + N2 * MAXDEG;          // 64*128
    float* h1     = (float*)(maskT + FUTURE * PAST);  // N1*200
    float* asrc1  = h1 + N1 * 200;                // N1*4
    float* adst1  = asrc1 + N1 * 4;               // N1*4
    float* y1     = adst1 + N1 * 4;               // N1
    float* P1T    = y1 + N1;                      // N1*64 as [b][k][p] (16B aligned)
    float* P2     = P1T + N1 * 64;                // N2*64
    float* h2b    = P2 + N2 * 64;                 // N2*4
    float* h2g    = h2b + N2 * 4;                 // N2*4
    float* n1w    = h2g + N2 * 4;                 // N1

    hipMemsetAsync(count1, 0, (N1 + N2) * sizeof(int), stream);
    k_prep<<<NB_CSR + NBP + NBF, 256, 0, stream>>>(
        cat1, num1, cat2, num2, emb0, emb1, emb2, g1_lin, g1_asrc, g1_adst, W,
        g2_lin, e1, e2, A, h1, asrc1, adst1, y1, P2, h2b,
        count1, slot1, count2, slot2, maskT);
    k_gat1<<<N1 / 4, 256, 0, stream>>>(count1, slot1, h1, asrc1, adst1, g1_b, W,
                                       P1T, n1w);
    k_attn<<<B_ * 16, 256, 0, stream>>>(P1T, P2, maskT, y1, n1w, h2b, g2_lin, h2g);
    k_gat2<<<N2 / 4, 256, 0, stream>>>(count2, slot2, h2g, g2_asrc, g2_adst, g2_b, out);
}

// Round 4
// 155.733 us; speedup vs baseline: 3.1931x; 1.0043x over previous
//
#include <hip/hip_runtime.h>

static constexpr int B_ = 64, PAST = 128, FUTURE = 64, F_ = 51;
static constexpr int N1 = B_ * PAST;    // 8192
static constexpr int N2 = B_ * FUTURE;  // 4096
static constexpr int E1 = N1 * 16;      // 131072
static constexpr int E2 = N2 * 16;      // 65536
static constexpr int MAXDEG = 64;
static constexpr int CSR_TOT = E1 + N1 + E2 + N2 + FUTURE * PAST;  // 217088
static constexpr int NB_CSR = CSR_TOT / 256;                       // 848
static constexpr int NPB = 16;                                     // nodes per block
static constexpr int NBP = N1 / NPB;                               // 512 past blocks
static constexpr int NBF = N2 / NPB;                               // 256 future blocks

// node feature t of _pre(): [emb0[c0] (16) | emb1[c1] (8) | emb2[c2] (24) | num (3)]
__device__ __forceinline__
float node_feat(const int* cat, const float* num, const float* e0, const float* e1,
                const float* e2, int n, int t) {
    if (t < 16) return e0[cat[n * 3 + 0] * 16 + t];
    if (t < 24) return e1[cat[n * 3 + 1] * 8 + (t - 16)];
    if (t < 48) return e2[cat[n * 3 + 2] * 24 + (t - 24)];
    return num[n * 3 + (t - 48)];
}

// K1 (fused): blocks [0,NB_CSR): CSR build (counts pre-zeroed by memset) + maskT.
// Blocks [NB_CSR, +NBP): 16 past nodes each -> h1 (interleaved [c*4+h]!), asrc1,
// adst1, y1. Blocks [.., +NBF): 16 future nodes -> P2 = x2@W, h2b = x2[:,:50]@g2_lin.
__global__ __launch_bounds__(256) void k_prep(
        const int* __restrict__ cat1, const float* __restrict__ num1,
        const int* __restrict__ cat2, const float* __restrict__ num2,
        const float* __restrict__ emb0, const float* __restrict__ emb1,
        const float* __restrict__ emb2,
        const float* __restrict__ g1_lin, const float* __restrict__ g1_asrc,
        const float* __restrict__ g1_adst, const float* __restrict__ W,
        const float* __restrict__ g2_lin,
        const int* __restrict__ e1, const int* __restrict__ e2,
        const int* __restrict__ A,
        float* __restrict__ h1, float* __restrict__ asrc1, float* __restrict__ adst1,
        float* __restrict__ y1, float* __restrict__ P2, float* __restrict__ h2b,
        int* __restrict__ count1, int* __restrict__ slot1,
        int* __restrict__ count2, int* __restrict__ slot2, int* __restrict__ maskT) {
    int blk = blockIdx.x, t = threadIdx.x;
    if (blk < NB_CSR) {                           // CSR part (independent of prep)
        int i = blk * 256 + t;
        if (i < E1) {
            int src = e1[i], dst = e1[E1 + i];
            int pos = atomicAdd(&count1[dst], 1);
            if (pos < MAXDEG) slot1[dst * MAXDEG + pos] = src;
        } else if (i < E1 + N1) {
            int n = i - E1;
            int pos = atomicAdd(&count1[n], 1);
            if (pos < MAXDEG) slot1[n * MAXDEG + pos] = n;
        } else if (i < E1 + N1 + E2) {
            int k = i - E1 - N1;
            int src = e2[k], dst = e2[E2 + k];
            int pos = atomicAdd(&count2[dst], 1);
            if (pos < MAXDEG) slot2[dst * MAXDEG + pos] = src;
        } else if (i < E1 + N1 + E2 + N2) {
            int n = i - E1 - N1 - E2;
            int pos = atomicAdd(&count2[n], 1);
            if (pos < MAXDEG) slot2[n * MAXDEG + pos] = n;
        } else if (i < CSR_TOT) {
            int k = i - (E1 + N1 + E2 + N2);      // k = f*128 + p
            int f = k >> 7, pp = k & 127;
            maskT[k] = A[pp * 192 + PAST + f];
        }
        return;
    }
    __shared__ __align__(16) float xr[NPB][64];   // [nn][j], j<51 valid, rest 0
    __shared__ float SredS[NPB][200];
    __shared__ float SredD[NPB][200];
    bool past = (blk < NB_CSR + NBP);
    int n0 = past ? (blk - NB_CSR) * NPB : (blk - NB_CSR - NBP) * NPB;
    // stage 16 x-rows (zero-padded to 64 cols so float4 reads never see garbage)
    #pragma unroll
    for (int r = 0; r < 4; ++r) {
        int i = t + r * 256, nn = i >> 6, tt = i & 63;
        float xv = 0.f;
        if (tt < F_) {
            xv = past ? node_feat(cat1, num1, emb0, emb1, emb2, n0 + nn, tt)
                      : node_feat(cat2, num2, emb0, emb1, emb2, n0 + nn, tt);
            if (past && tt == 50) y1[n0 + nn] = xv;   // y_past = x[:, 50]
        }
        xr[nn][tt] = xv;
    }
    __syncthreads();
    const float4* xr4 = (const float4*)&xr[0][0];     // [nn*16 + j4]
    if (past) {
        if (t < 200) {
            float acc[NPB];
            #pragma unroll
            for (int nn = 0; nn < NPB; ++nn) acc[nn] = 0.f;
            #pragma unroll
            for (int j4 = 0; j4 < 13; ++j4) {         // j = 4*j4 + {0,1,2,3}
                int j = j4 * 4;
                float g0 = g1_lin[(j + 0) * 200 + t];
                float g1 = g1_lin[(j + 1) * 200 + t];
                float g2 = g1_lin[(j + 2) * 200 + t];
                float g3 = (j + 3 < F_) ? g1_lin[(j + 3) * 200 + t] : 0.f;
                #pragma unroll
                for (int nn = 0; nn < NPB; ++nn) {
                    float4 xv = xr4[nn * 16 + j4];    // broadcast LDS read
                    acc[nn] = fmaf(xv.x, g0, acc[nn]);
                    acc[nn] = fmaf(xv.y, g1, acc[nn]);
                    acc[nn] = fmaf(xv.z, g2, acc[nn]);
                    acc[nn] = fmaf(xv.w, g3, acc[nn]);
                }
            }
            float as_ = g1_asrc[t], ad_ = g1_adst[t]; // flat t == h*50+c
            int hh = t / 50, cc = t - hh * 50;
            int c4h = cc * 4 + hh;                    // interleaved h1 col index
            #pragma unroll
            for (int nn = 0; nn < NPB; ++nn) {
                h1[(n0 + nn) * 200 + c4h] = acc[nn];
                SredS[nn][t] = acc[nn] * as_;
                SredD[nn][t] = acc[nn] * ad_;
            }
        }
        __syncthreads();
        if (t < 128) {                                // (nn, h, S/D) per thread
            int nn = t >> 3, h = (t >> 1) & 3;
            const float* row = (t & 1) ? &SredD[nn][h * 50] : &SredS[nn][h * 50];
            float s = 0.f;
            for (int c = 0; c < 50; ++c) s += row[c];
            float* dstp = (t & 1) ? adst1 : asrc1;
            dstp[(n0 + nn) * 4 + h] = s;
        }
    } else {
        if (t < 64) {                                 // P2 = x2[:, :50] @ W
            float acc[NPB];
            #pragma unroll
            for (int nn = 0; nn < NPB; ++nn) acc[nn] = 0.f;
            #pragma unroll
            for (int j4 = 0; j4 < 13; ++j4) {
                int j = j4 * 4;
                float g0 = (j + 0 < 50) ? W[(j + 0) * 64 + t] : 0.f;
                float g1 = (j + 1 < 50) ? W[(j + 1) * 64 + t] : 0.f;
                float g2 = (j + 2 < 50) ? W[(j + 2) * 64 + t] : 0.f;
                float g3 = (j + 3 < 50) ? W[(j + 3) * 64 + t] : 0.f;
                #pragma unroll
                for (int nn = 0; nn < NPB; ++nn) {
                    float4 xv = xr4[nn * 16 + j4];
                    acc[nn] = fmaf(xv.x, g0, acc[nn]);
                    acc[nn] = fmaf(xv.y, g1, acc[nn]);
                    acc[nn] = fmaf(xv.z, g2, acc[nn]);
                    acc[nn] = fmaf(xv.w, g3, acc[nn]);
                }
            }
            #pragma unroll
            for (int nn = 0; nn < NPB; ++nn) P2[(n0 + nn) * 64 + t] = acc[nn];
        } else if (t < 128) {                         // h2b: one (node, head) each
            int nn = (t - 64) >> 2, h = (t - 64) & 3;
            float acc = 0.f;
            for (int j = 0; j < 50; ++j) acc += xr[nn][j] * g2_lin[j * 4 + h];
            h2b[(n0 + nn) * 4 + h] = acc;
        }
    }
}

// K2: GAT1 aggregation, one wave per dst node; fused x1 -> P projection.
// h1 gather is ONE dwordx4 per edge per lane (interleaved layout).
__global__ __launch_bounds__(256) void k_gat1(
        const int* __restrict__ count1, const int* __restrict__ slot1,
        const float* __restrict__ h1, const float* __restrict__ asrc1,
        const float* __restrict__ adst1, const float* __restrict__ g1_b,
        const float* __restrict__ W, float* __restrict__ P1T,
        float* __restrict__ n1w) {
    __shared__ int    Ssrc[4][64];
    __shared__ float4 Sw[4][64];
    __shared__ float  Sx[4][64];
    int t = threadIdx.x, lane = t & 63, wv = t >> 6;
    int n = (blockIdx.x * 256 + t) >> 6;          // one node per wave (grid exact)
    int deg = min(count1[n], MAXDEG);
    int my_src = (lane < deg) ? slot1[n * MAXDEG + lane] : 0;
    float4 ad4 = *(const float4*)&adst1[n * 4];
    float ex0 = 0.f, ex1 = 0.f, ex2 = 0.f, ex3 = 0.f;
    if (lane < deg) {
        float4 as4 = *(const float4*)&asrc1[my_src * 4];   // one dwordx4 gather
        float e0 = as4.x + ad4.x;
        float e1 = as4.y + ad4.y;
        float e2 = as4.z + ad4.z;
        float e3 = as4.w + ad4.w;
        e0 = e0 >= 0.f ? e0 : 0.2f * e0;  ex0 = __expf(e0);
        e1 = e1 >= 0.f ? e1 : 0.2f * e1;  ex1 = __expf(e1);
        e2 = e2 >= 0.f ? e2 : 0.2f * e2;  ex2 = __expf(e2);
        e3 = e3 >= 0.f ? e3 : 0.2f * e3;  ex3 = __expf(e3);
    }
    float s0 = ex0, s1 = ex1, s2 = ex2, s3 = ex3;
    #pragma unroll
    for (int m = 32; m >= 1; m >>= 1) {
        s0 += __shfl_xor(s0, m);
        s1 += __shfl_xor(s1, m);
        s2 += __shfl_xor(s2, m);
        s3 += __shfl_xor(s3, m);
    }
    Ssrc[wv][lane] = my_src;
    Sw[wv][lane] = make_float4(ex0 / (s0 + 1e-16f), ex1 / (s1 + 1e-16f),
                               ex2 / (s2 + 1e-16f), ex3 / (s3 + 1e-16f));
    __syncthreads();
    float acc0 = 0.f, acc1 = 0.f, acc2 = 0.f, acc3 = 0.f;
    for (int i = 0; i < deg; ++i) {
        int srci = Ssrc[wv][i];
        float4 w = Sw[wv][i];                     // broadcast, conflict-free
        if (lane < 50) {                          // 800B contiguous across 50 lanes
            float4 v = *(const float4*)&h1[srci * 200 + lane * 4];
            acc0 = fmaf(w.x, v.x, acc0);
            acc1 = fmaf(w.y, v.y, acc1);
            acc2 = fmaf(w.z, v.z, acc2);
            acc3 = fmaf(w.w, v.w, acc3);
        }
    }
    if (lane < 50)
        Sx[wv][lane] = 0.25f * (acc0 + acc1 + acc2 + acc3) + g1_b[lane];
    __syncthreads();
    float a = 0.f;
    for (int j = 0; j < 50; ++j) a += Sx[wv][j] * W[j * 64 + lane];
    int b = n >> 7, p = n & 127;
    P1T[b * 8192 + lane * 128 + p] = a;           // transposed store [b][k][p]
    float sq = a * a;                             // ||P1 row||^2 via wave reduce
    #pragma unroll
    for (int m = 32; m >= 1; m >>= 1) sq += __shfl_xor(sq, m);
    if (lane == 0) n1w[n] = sq;
}

// K3: attention + tmp + h2 finalize. One f per wave; norm expansion:
// alpha_p = 2*dot(P1_p,P2_f) - ||P1_p||^2 (||P2_f||^2 constant per row, dropped).
__global__ __launch_bounds__(256) void k_attn(
        const float* __restrict__ P1T, const float* __restrict__ P2,
        const int* __restrict__ maskT, const float* __restrict__ y1,
        const float* __restrict__ n1w, const float* __restrict__ h2b,
        const float* __restrict__ g2_lin, float* __restrict__ h2g) {
    __shared__ __align__(16) float P1s[8192];     // [k][p] linear
    __shared__ __align__(16) float ys[128];
    __shared__ __align__(16) float n1s[128];
    int b = blockIdx.x >> 4, fg = blockIdx.x & 15;
    int t = threadIdx.x, lane = t & 63, wv = t >> 6;
    const float4* src4 = (const float4*)(P1T + b * 8192);
    float4* dst4 = (float4*)P1s;
    #pragma unroll
    for (int i = 0; i < 8; ++i) dst4[t + i * 256] = src4[t + i * 256];
    if (t < 128) {
        ys[t]  = y1[b * 128 + t];
        n1s[t] = n1w[b * 128 + t];
    }
    __syncthreads();
    int f = (fg << 2) + wv;
    int q = b * 64 + f;
    float p2k = P2[q * 64 + lane];                // lane holds k-th component
    float dota = 0.f, dotb = 0.f;
    const float2* P12 = (const float2*)P1s;       // element (k, p=2*lane[+1])
    #pragma unroll
    for (int k = 0; k < 64; ++k) {
        float bk = __shfl(p2k, k);
        float2 v = P12[k * 64 + lane];
        dota += v.x * bk;
        dotb += v.y * bk;
    }
    int2  mm  = ((const int2*)maskT)[f * 64 + lane];
    float2 nv = ((const float2*)n1s)[lane];
    float va = mm.x ? (2.f * dota - nv.x) : -1e30f;
    float vb = mm.y ? (2.f * dotb - nv.y) : -1e30f;
    float mx = fmaxf(va, vb);
    #pragma unroll
    for (int m = 32; m >= 1; m >>= 1) mx = fmaxf(mx, __shfl_xor(mx, m));
    float wa = mm.x ? __expf(va - mx) : 0.f;
    float wb = mm.y ? __expf(vb - mx) : 0.f;
    float2 yv = ((const float2*)ys)[lane];
    float sw = wa + wb;
    float sy = wa * yv.x + wb * yv.y;
    #pragma unroll
    for (int m = 32; m >= 1; m >>= 1) {
        sw += __shfl_xor(sw, m);
        sy += __shfl_xor(sy, m);
    }
    float tsh = sy / sw;
    if (lane == 0) {                              // h2 = h2base + tmp * g2_lin[50]
        float4 hb = *(const float4*)&h2b[q * 4];
        float4 gw = *(const float4*)&g2_lin[200];
        float4 r;
        r.x = fmaf(tsh, gw.x, hb.x);
        r.y = fmaf(tsh, gw.y, hb.y);
        r.z = fmaf(tsh, gw.z, hb.z);
        r.w = fmaf(tsh, gw.w, hb.w);
        *(float4*)&h2g[q * 4] = r;
    }
}

// K4: GAT2 aggregation (out_ch=1): one wave per dst node. float4 h2g gathers.
__global__ __launch_bounds__(256) void k_gat2(
        const int* __restrict__ count2, const int* __restrict__ slot2,
        const float* __restrict__ h2g, const float* __restrict__ g2_asrc,
        const float* __restrict__ g2_adst, const float* __restrict__ g2_b,
        float* __restrict__ out) {
    int wave = (blockIdx.x * blockDim.x + threadIdx.x) >> 6;
    int lane = threadIdx.x & 63;
    if (wave >= N2) return;
    int n = wave;
    int deg = min(count2[n], MAXDEG);
    int my_src = (lane < deg) ? slot2[n * MAXDEG + lane] : 0;
    float4 hn4 = *(const float4*)&h2g[n * 4];
    float ex[4], nm[4], adterm[4], as[4];
    const float hn[4] = {hn4.x, hn4.y, hn4.z, hn4.w};
    #pragma unroll
    for (int h = 0; h < 4; ++h) {
        as[h] = g2_asrc[h];
        adterm[h] = hn[h] * g2_adst[h];
        ex[h] = 0.f; nm[h] = 0.f;
    }
    if (lane < deg) {
        float4 hs4 = *(const float4*)&h2g[my_src * 4];     // one dwordx4 gather
        const float hs[4] = {hs4.x, hs4.y, hs4.z, hs4.w};
        #pragma unroll
        for (int h = 0; h < 4; ++h) {
            float e = hs[h] * as[h] + adterm[h];
            e = e >= 0.f ? e : 0.2f * e;
            float xv = __expf(e);
            ex[h] = xv;
            nm[h] = xv * hs[h];
        }
    }
    #pragma unroll
    for (int m = 32; m >= 1; m >>= 1) {
        #pragma unroll
        for (int h = 0; h < 4; ++h) {
            ex[h] += __shfl_xor(ex[h], m);
            nm[h] += __shfl_xor(nm[h], m);
        }
    }
    if (lane == 0) {
        float o = 0.f;
        #pragma unroll
        for (int h = 0; h < 4; ++h) o += nm[h] / (ex[h] + 1e-16f);
        out[n] = 0.25f * o + g2_b[0];
    }
}

extern "C" void kernel_launch(void* const* d_in, const int* in_sizes, int n_in,
                              void* d_out, int out_size, void* d_ws, size_t ws_size,
                              hipStream_t stream) {
    const int*   cat1    = (const int*)  d_in[0];
    const float* num1    = (const float*)d_in[1];
    const int*   cat2    = (const int*)  d_in[2];
    const float* num2    = (const float*)d_in[3];
    const int*   e1      = (const int*)  d_in[4];
    const int*   e2      = (const int*)  d_in[5];
    const int*   A       = (const int*)  d_in[6];
    const float* emb0    = (const float*)d_in[7];
    const float* emb1    = (const float*)d_in[8];
    const float* emb2    = (const float*)d_in[9];
    const float* g1_lin  = (const float*)d_in[10];
    const float* g1_asrc = (const float*)d_in[11];
    const float* g1_adst = (const float*)d_in[12];
    const float* g1_b    = (const float*)d_in[13];
    const float* g2_lin  = (const float*)d_in[14];
    const float* g2_asrc = (const float*)d_in[15];
    const float* g2_adst = (const float*)d_in[16];
    const float* g2_b    = (const float*)d_in[17];
    const float* W       = (const float*)d_in[18];
    float* out = (float*)d_out;

    // workspace layout (fp32/int32 elements)
    int*   count1 = (int*)d_ws;                   // N1  (count1+count2 contiguous!)
    int*   count2 = count1 + N1;                  // N2
    int*   slot1  = count2 + N2;                  // N1*64
    int*   slot2  = slot1 + N1 * MAXDEG;          // N2*64
    int*   maskT  = slot2 + N2 * MAXDEG;          // 64*128
    float* h1     = (float*)(maskT + FUTURE * PAST);  // N1*200 interleaved [c*4+h]
    float* asrc1  = h1 + N1 * 200;                // N1*4
    float* adst1  = asrc1 + N1 * 4;               // N1*4
    float* y1     = adst1 + N1 * 4;               // N1
    float* P1T    = y1 + N1;                      // N1*64 as [b][k][p] (16B aligned)
    float* P2     = P1T + N1 * 64;                // N2*64
    float* h2b    = P2 + N2 * 64;                 // N2*4
    float* h2g    = h2b + N2 * 4;                 // N2*4
    float* n1w    = h2g + N2 * 4;                 // N1

    hipMemsetAsync(count1, 0, (N1 + N2) * sizeof(int), stream);
    k_prep<<<NB_CSR + NBP + NBF, 256, 0, stream>>>(
        cat1, num1, cat2, num2, emb0, emb1, emb2, g1_lin, g1_asrc, g1_adst, W,
        g2_lin, e1, e2, A, h1, asrc1, adst1, y1, P2, h2b,
        count1, slot1, count2, slot2, maskT);
    k_gat1<<<N1 / 4, 256, 0, stream>>>(count1, slot1, h1, asrc1, adst1, g1_b, W,
                                       P1T, n1w);
    k_attn<<<B_ * 16, 256, 0, stream>>>(P1T, P2, maskT, y1, n1w, h2b, g2_lin, h2g);
    k_gat2<<<N2 / 4, 256, 0, stream>>>(count2, slot2, h2g, g2_asrc, g2_adst, g2_b, out);
}